// Round 5
// baseline (71.662 us; speedup 1.0000x reference)
//
#include <hip/hip_runtime.h>
#include <hip/hip_bf16.h>

#define T_TOTAL 200000
#define INV2PI 0.15915494309189535f

typedef float v2f __attribute__((ext_vector_type(2)));

// Parameter block layout (floats):
// [0 .. 39]     : layer0 interleaved pairs (ww0', ph0') x 20   (NOT 0.25-shifted)
// [40 .. 59]    : A0 x 20
// [60 .. 1339]  : layer1, per n (n<20) a 64-float block at 60+64n:
//                 [+m] = ww1'(n,m), [+32+m] = ph1'(n,m)+0.25, m<32 (pad m>=25: ww=0, ph=0.25)
// [1340 .. 2939]: layer2, per n (n<25) a 64-float block at 1340+64n:
//                 [+m] = ww2'(n,m), [+32+m] = ph2'(n,m)+0.25, m<32 (pad m>=30)
// [2940 .. 2999]: layer3 interleaved pairs x 30                (NOT shifted)
// ww'/ph' are pre-divided by 2*pi (revolutions). The +0.25 shift on layers 1/2
// enables sin(2*pi*f) = cos(2*pi*h), h = fract(rev)-0.5 : even poly, no abs/sign.
__device__ float g_P[3000];

__device__ __forceinline__ float relu_f(float x) { return fmaxf(x, 0.0f); }

__device__ __forceinline__ float sin_rev(float rev) {
    return __builtin_amdgcn_sinf(__builtin_amdgcn_fractf(rev));
}

// cos(2*pi*h) for h in [-0.5,0.5], even Taylor in u=h^2 through u^6.
// b_k = (-1)^k (2pi)^(2k) / (2k)!  ; truncation error <= pi^14/14! = 1.05e-4.
__device__ __forceinline__ v2f sin2pi_pk(v2f rev) {
    v2f g;
    g[0] = __builtin_amdgcn_fractf(rev[0]);
    g[1] = __builtin_amdgcn_fractf(rev[1]);
    v2f h = g - 0.5f;          // v_pk_add
    v2f u = h * h;             // v_pk_mul
    const float B6 =  7.9035364f;
    const float B5 = -26.4262568f;
    const float B4 =  60.2446414f;
    const float B3 = -85.4568172f;
    const float B2 =  64.9393940f;
    const float B1 = -19.7392088f;
    const float B0 =  1.0f;
    v2f p = u * B6 + B5;       // contract -> v_pk_fma chain
    p = p * u + B4;
    p = p * u + B3;
    p = p * u + B2;
    p = p * u + B1;
    p = p * u + B0;
    return p;
}

__global__ void prep_kernel(
    const float* __restrict__ A0,
    const float* __restrict__ w0, const float* __restrict__ phi0,
    const float* __restrict__ wc0, const float* __restrict__ phic0,
    const float* __restrict__ w1, const float* __restrict__ phi1,
    const float* __restrict__ wc1, const float* __restrict__ phic1,
    const float* __restrict__ w2, const float* __restrict__ phi2,
    const float* __restrict__ wc2, const float* __restrict__ phic2,
    const float* __restrict__ w3, const float* __restrict__ phi3,
    const float* __restrict__ wc3, const float* __restrict__ phic3)
{
    const int tid = blockIdx.x * blockDim.x + threadIdx.x;
    const int stride = blockDim.x * gridDim.x;

    const float ws0 = relu_f(wc0[0]), ps0 = relu_f(phic0[0]);
    const float ws1 = relu_f(wc1[0]), ps1 = relu_f(phic1[0]);
    const float ws2 = relu_f(wc2[0]), ps2 = relu_f(phic2[0]);
    const float ws3 = relu_f(wc3[0]), ps3 = relu_f(phic3[0]);

    for (int n = tid; n < 20; n += stride) {
        g_P[2 * n]     = (relu_f(w0[n])   + ws0) * INV2PI;
        g_P[2 * n + 1] = (relu_f(phi0[n]) + ps0) * INV2PI;
        g_P[40 + n]    = A0[n];
    }
    // layer1: 20 n-blocks of 32 padded m-slots (ww | ph, split halves)
    for (int k = tid; k < 20 * 32; k += stride) {
        const int n = k >> 5, m = k & 31;
        float wwv = 0.0f, phv = 0.25f;
        if (m < 25) {
            const int s = m * 20 + n;              // source row-major (m,n)
            wwv = (relu_f(w1[s])   + ws1) * INV2PI;
            phv = (relu_f(phi1[s]) + ps1) * INV2PI + 0.25f;
        }
        g_P[60 + 64 * n + m]      = wwv;
        g_P[60 + 64 * n + 32 + m] = phv;
    }
    // layer2: 25 n-blocks of 32 padded m-slots
    for (int k = tid; k < 25 * 32; k += stride) {
        const int n = k >> 5, m = k & 31;
        float wwv = 0.0f, phv = 0.25f;
        if (m < 30) {
            const int s = m * 25 + n;
            wwv = (relu_f(w2[s])   + ws2) * INV2PI;
            phv = (relu_f(phi2[s]) + ps2) * INV2PI + 0.25f;
        }
        g_P[1340 + 64 * n + m]      = wwv;
        g_P[1340 + 64 * n + 32 + m] = phv;
    }
    for (int k = tid; k < 30; k += stride) {
        g_P[2940 + 2 * k]     = (relu_f(w3[k])   + ws3) * INV2PI;
        g_P[2940 + 2 * k + 1] = (relu_f(phi3[k]) + ps3) * INV2PI;
    }
}

// block = 256 = 4 waves per 64 t-values; wave w owns m = 8w..8w+7 as 4 packed
// pairs in layers 1/2 (padded to 32 m-slots). All heavy sines go through the
// packed-f32 cos-poly (v_pk_fma_f32) instead of the ~16-cycle v_sin.
__launch_bounds__(256)
__global__ void wave_main(float* __restrict__ out)
{
    __shared__ float sh0[20 * 64];
    __shared__ float sh1[25 * 64];
    __shared__ float sh2[30 * 64];

    const int tid = threadIdx.x;
    const int l = tid & 63;
    const int w = __builtin_amdgcn_readfirstlane(tid >> 6);
    const int t = blockIdx.x * 64 + l;              // grid exact: 3125*64
    const float tv = fmaf((float)t, 999.0f / 199999.0f, 1.0f);
    v2f tv2; tv2[0] = tv; tv2[1] = tv;

    // ---- layer 0: wave w computes n = 5w .. 5w+4 (v_sin; 1.5% of work) ----
    {
        const float* __restrict__ p = &g_P[10 * w];
        const float* __restrict__ a = &g_P[40 + 5 * w];
#pragma unroll
        for (int i = 0; i < 5; ++i) {
            float rev = fmaf(p[2 * i], tv, p[2 * i + 1]);
            sh0[(5 * w + i) * 64 + l] = a[i] * sin_rev(rev);
        }
    }
    __syncthreads();

    // ---- layer 1: wave w owns m-pairs j=0..3 (m = 8w+2j+c) ----
    v2f acc1[4] = {};
    float sum0 = 0.0f;
#pragma clang loop unroll(disable)
    for (int n = 0; n < 20; ++n) {
        const float s0n = sh0[n * 64 + l];
        sum0 += s0n;
        v2f s0d; s0d[0] = s0n; s0d[1] = s0n;
        const v2f* __restrict__ wwp = (const v2f*)&g_P[60 + 64 * n + 8 * w];
        const v2f* __restrict__ php = (const v2f*)&g_P[60 + 64 * n + 32 + 8 * w];
#pragma unroll
        for (int j = 0; j < 4; ++j) {
            v2f rev = wwp[j] * tv2 + php[j];
            v2f sn = sin2pi_pk(rev);
            acc1[j] = sn * s0d + acc1[j];
        }
    }
#pragma unroll
    for (int j = 0; j < 4; ++j) {
#pragma unroll
        for (int c = 0; c < 2; ++c) {
            const int m = 8 * w + 2 * j + c;        // wave-uniform condition
            if (m < 25) sh1[m * 64 + l] = fmaf(0.5f, acc1[j][c], 0.5f * sum0);
        }
    }
    __syncthreads();

    // ---- layer 2: wave w owns m-pairs j=0..3 (m = 8w+2j+c) ----
    v2f acc2[4] = {};
    float sum1 = 0.0f;
#pragma clang loop unroll(disable)
    for (int n = 0; n < 25; ++n) {
        const float s1n = sh1[n * 64 + l];
        sum1 += s1n;
        v2f s1d; s1d[0] = s1n; s1d[1] = s1n;
        const v2f* __restrict__ wwp = (const v2f*)&g_P[1340 + 64 * n + 8 * w];
        const v2f* __restrict__ php = (const v2f*)&g_P[1340 + 64 * n + 32 + 8 * w];
#pragma unroll
        for (int j = 0; j < 4; ++j) {
            v2f rev = wwp[j] * tv2 + php[j];
            v2f sn = sin2pi_pk(rev);
            acc2[j] = sn * s1d + acc2[j];
        }
    }
#pragma unroll
    for (int j = 0; j < 4; ++j) {
#pragma unroll
        for (int c = 0; c < 2; ++c) {
            const int m = 8 * w + 2 * j + c;
            if (m < 30) sh2[m * 64 + l] = fmaf(0.5f, acc2[j][c], 0.5f * sum1);
        }
    }
    __syncthreads();

    // ---- layer 3: wave 0 only (30 sines, v_sin) ----
    if (w == 0) {
        float acc3 = 0.0f, sum2 = 0.0f;
#pragma unroll
        for (int n = 0; n < 30; ++n) {
            const float s2n = sh2[n * 64 + l];
            sum2 += s2n;
            float rev = fmaf(g_P[2940 + 2 * n], tv, g_P[2940 + 2 * n + 1]);
            acc3 = fmaf(sin_rev(rev), s2n, acc3);
        }
        out[t] = fmaf(0.5f, acc3, 0.5f * sum2);
    }
}

extern "C" void kernel_launch(void* const* d_in, const int* in_sizes, int n_in,
                              void* d_out, int out_size, void* d_ws, size_t ws_size,
                              hipStream_t stream) {
    (void)in_sizes; (void)n_in; (void)d_ws; (void)ws_size; (void)out_size;
    const float* A0    = (const float*)d_in[1];
    const float* w0    = (const float*)d_in[2];
    const float* phi0  = (const float*)d_in[3];
    const float* wc0   = (const float*)d_in[4];
    const float* phic0 = (const float*)d_in[5];
    const float* w1    = (const float*)d_in[6];
    const float* phi1  = (const float*)d_in[7];
    const float* wc1   = (const float*)d_in[8];
    const float* phic1 = (const float*)d_in[9];
    const float* w2    = (const float*)d_in[10];
    const float* phi2  = (const float*)d_in[11];
    const float* wc2   = (const float*)d_in[12];
    const float* phic2 = (const float*)d_in[13];
    const float* w3    = (const float*)d_in[14];
    const float* phi3  = (const float*)d_in[15];
    const float* wc3   = (const float*)d_in[16];
    const float* phic3 = (const float*)d_in[17];

    float* out = (float*)d_out;

    hipLaunchKernelGGL(prep_kernel, dim3(11), dim3(256), 0, stream,
                       A0, w0, phi0, wc0, phic0,
                       w1, phi1, wc1, phic1,
                       w2, phi2, wc2, phic2,
                       w3, phi3, wc3, phic3);

    const int grid = T_TOTAL / 64;   // 3125, exact
    hipLaunchKernelGGL(wave_main, dim3(grid), dim3(256), 0, stream, out);
}

// Round 6
// 54.693 us; speedup vs baseline: 1.3103x; 1.3103x over previous
//
#include <hip/hip_runtime.h>
#include <hip/hip_bf16.h>

#define T_TOTAL 200000

typedef float v4f __attribute__((ext_vector_type(4)));

// Parameter block layout (floats), all phases in REVOLUTIONS, pre +0.25-shifted
// so sin(theta) = cos(2*pi*(fract(rev)-0.5)) (even poly, no sign fixup):
// [0..19]    ww0' (rev per tv-unit)    [20..39] ph0'+0.25   [40..59] C0=2cos(w*64d)
// [60..79]   A0
// [80..1999] layer1: per n<20, 96-float block at 80+96n:
//            [+m]=ww1'(n,m)  [+32+m]=ph1'+0.25  [+64+m]=C1, m<32
//            pads m>=25: ww=0, ph=0.25 (-> sin=0), C=2
// [2000..4399] layer2: per n<25, 96-float block at 2000+96n (pads m>=30)
// [4400..4495] layer3: [+k]=ww3' [+32+k]=ph3'+0.25 [+64+k]=C3, k<32 (pads 0)
__device__ float g_P[4496];

// sin(2*pi*rev) via even minimax poly: cos(2*pi*h), h = fract(rev)-0.5.
// Chebyshev-economized deg-8 (Bessel J_k(pi) expansion), |err| ~= 4e-5.
__device__ __forceinline__ float sinp(float rev) {
    float g = __builtin_amdgcn_fractf(rev);
    float h = g - 0.5f;
    float u = h * h;
    float p = fmaf(45.621248f, u, -82.391040f);
    p = fmaf(p, u, 64.671616f);
    p = fmaf(p, u, -19.730960f);
    p = fmaf(p, u, 0.9999618f);
    return p;
}

__global__ void prep_kernel(
    const float* __restrict__ A0,
    const float* __restrict__ w0, const float* __restrict__ phi0,
    const float* __restrict__ wc0, const float* __restrict__ phic0,
    const float* __restrict__ w1, const float* __restrict__ phi1,
    const float* __restrict__ wc1, const float* __restrict__ phic1,
    const float* __restrict__ w2, const float* __restrict__ phi2,
    const float* __restrict__ wc2, const float* __restrict__ phic2,
    const float* __restrict__ w3, const float* __restrict__ phi3,
    const float* __restrict__ wc3, const float* __restrict__ phic3)
{
    const int tid = blockIdx.x * blockDim.x + threadIdx.x;
    const int stride = blockDim.x * gridDim.x;

    const double I2PI = 0.15915494309189535;
    const double D64  = 64.0 * 999.0 / 199999.0;   // t-step between j's

    const double ws0 = fmax((double)wc0[0], 0.0), ps0 = fmax((double)phic0[0], 0.0);
    const double ws1 = fmax((double)wc1[0], 0.0), ps1 = fmax((double)phic1[0], 0.0);
    const double ws2 = fmax((double)wc2[0], 0.0), ps2 = fmax((double)phic2[0], 0.0);
    const double ws3 = fmax((double)wc3[0], 0.0), ps3 = fmax((double)phic3[0], 0.0);

    for (int n = tid; n < 20; n += stride) {
        double wr = fmax((double)w0[n], 0.0) + ws0;
        g_P[n]      = (float)(wr * I2PI);
        g_P[20 + n] = (float)((fmax((double)phi0[n], 0.0) + ps0) * I2PI + 0.25);
        g_P[40 + n] = (float)(2.0 * cos(wr * D64));
        g_P[60 + n] = A0[n];
    }
    for (int k = tid; k < 20 * 32; k += stride) {
        const int n = k >> 5, m = k & 31;
        float wwf = 0.0f, phf = 0.25f, cf = 2.0f;
        if (m < 25) {
            const int s = m * 20 + n;
            double wr = fmax((double)w1[s], 0.0) + ws1;
            wwf = (float)(wr * I2PI);
            phf = (float)((fmax((double)phi1[s], 0.0) + ps1) * I2PI + 0.25);
            cf  = (float)(2.0 * cos(wr * D64));
        }
        g_P[80 + 96 * n + m]      = wwf;
        g_P[80 + 96 * n + 32 + m] = phf;
        g_P[80 + 96 * n + 64 + m] = cf;
    }
    for (int k = tid; k < 25 * 32; k += stride) {
        const int n = k >> 5, m = k & 31;
        float wwf = 0.0f, phf = 0.25f, cf = 2.0f;
        if (m < 30) {
            const int s = m * 25 + n;
            double wr = fmax((double)w2[s], 0.0) + ws2;
            wwf = (float)(wr * I2PI);
            phf = (float)((fmax((double)phi2[s], 0.0) + ps2) * I2PI + 0.25);
            cf  = (float)(2.0 * cos(wr * D64));
        }
        g_P[2000 + 96 * n + m]      = wwf;
        g_P[2000 + 96 * n + 32 + m] = phf;
        g_P[2000 + 96 * n + 64 + m] = cf;
    }
    for (int k = tid; k < 32; k += stride) {
        float wwf = 0.0f, phf = 0.0f, cf = 2.0f;   // pads guarded in kernel anyway
        if (k < 30) {
            double wr = fmax((double)w3[k], 0.0) + ws3;
            wwf = (float)(wr * I2PI);
            phf = (float)((fmax((double)phi3[k], 0.0) + ps3) * I2PI + 0.25);
            cf  = (float)(2.0 * cos(wr * D64));
        }
        g_P[4400 + k]      = wwf;
        g_P[4400 + 32 + k] = phf;
        g_P[4400 + 64 + k] = cf;
    }
}

// Block = 256 threads = 4 waves; covers 256 t-values: t = tb + lane + 64*j,
// j=0..3 per thread (stride-64 -> one Chebyshev coefficient per (m,n)).
// Per (m,n): sines at j=0,1 by direct poly eval, j=2,3 by 1-fma recurrence
// x_{j+1} = C*x_j - x_{j-1}. Wave w owns m = 8w..8w+7 in layers 1-3.
__launch_bounds__(256)
__global__ void wave_main(float* __restrict__ out)
{
    __shared__ float sh0[20][64][4];   // s0[n][lane][j]
    __shared__ float sh1[25][64][4];   // s1[m][lane][j]
    __shared__ float shp[4][64][4];    // layer-3 per-wave partials

    const int l = threadIdx.x & 63;
    const int w = __builtin_amdgcn_readfirstlane(threadIdx.x >> 6);
    const int tb = blockIdx.x * 256;
    const float STEP = 999.0f / 199999.0f;

    float tv[4];
#pragma unroll
    for (int j = 0; j < 4; ++j)
        tv[j] = fmaf((float)(tb + l + 64 * j), STEP, 1.0f);

    // ---- layer 0: wave w computes n = 5w..5w+4 ----
#pragma unroll
    for (int i = 0; i < 5; ++i) {
        const int n = 5 * w + i;
        const float ww = g_P[n], ph = g_P[20 + n], C = g_P[40 + n], A = g_P[60 + n];
        float x0 = A * sinp(fmaf(ww, tv[0], ph));
        float x1 = A * sinp(fmaf(ww, tv[1], ph));
        float x2 = fmaf(C, x1, -x0);
        float x3 = fmaf(C, x2, -x1);
        *(v4f*)&sh0[n][l][0] = (v4f){x0, x1, x2, x3};
    }
    __syncthreads();

    // ---- layer 1: wave w owns m = 8w+k, k<8 (pad 32) ----
    float acc1[8][4] = {};
    float sum0[4] = {0.f, 0.f, 0.f, 0.f};
#pragma clang loop unroll(disable)
    for (int n = 0; n < 20; ++n) {
        const v4f s0 = *(const v4f*)&sh0[n][l][0];
#pragma unroll
        for (int j = 0; j < 4; ++j) sum0[j] += s0[j];
        const float* __restrict__ pb = &g_P[80 + 96 * n + 8 * w];
#pragma unroll
        for (int k = 0; k < 8; ++k) {
            const float ww = pb[k], ph = pb[32 + k], C = pb[64 + k];
            float x0 = sinp(fmaf(ww, tv[0], ph));
            float x1 = sinp(fmaf(ww, tv[1], ph));
            float x2 = fmaf(C, x1, -x0);
            float x3 = fmaf(C, x2, -x1);
            acc1[k][0] = fmaf(x0, s0[0], acc1[k][0]);
            acc1[k][1] = fmaf(x1, s0[1], acc1[k][1]);
            acc1[k][2] = fmaf(x2, s0[2], acc1[k][2]);
            acc1[k][3] = fmaf(x3, s0[3], acc1[k][3]);
        }
    }
#pragma unroll
    for (int k = 0; k < 8; ++k) {
        if (8 * w + k < 25) {          // wave-uniform guard
            v4f v;
#pragma unroll
            for (int j = 0; j < 4; ++j) v[j] = fmaf(0.5f, acc1[k][j], 0.5f * sum0[j]);
            *(v4f*)&sh1[8 * w + k][l][0] = v;
        }
    }
    __syncthreads();

    // ---- layer 2: wave w owns m = 8w+k, k<8 (pad 32); s2 stays in regs ----
    float acc2[8][4] = {};
    float sum1[4] = {0.f, 0.f, 0.f, 0.f};
#pragma clang loop unroll(disable)
    for (int n = 0; n < 25; ++n) {
        const v4f s1 = *(const v4f*)&sh1[n][l][0];
#pragma unroll
        for (int j = 0; j < 4; ++j) sum1[j] += s1[j];
        const float* __restrict__ pb = &g_P[2000 + 96 * n + 8 * w];
#pragma unroll
        for (int k = 0; k < 8; ++k) {
            const float ww = pb[k], ph = pb[32 + k], C = pb[64 + k];
            float x0 = sinp(fmaf(ww, tv[0], ph));
            float x1 = sinp(fmaf(ww, tv[1], ph));
            float x2 = fmaf(C, x1, -x0);
            float x3 = fmaf(C, x2, -x1);
            acc2[k][0] = fmaf(x0, s1[0], acc2[k][0]);
            acc2[k][1] = fmaf(x1, s1[1], acc2[k][1]);
            acc2[k][2] = fmaf(x2, s1[2], acc2[k][2]);
            acc2[k][3] = fmaf(x3, s1[3], acc2[k][3]);
        }
    }
    float s2r[8][4];
#pragma unroll
    for (int k = 0; k < 8; ++k)
#pragma unroll
        for (int j = 0; j < 4; ++j)
            s2r[k][j] = fmaf(0.5f, acc2[k][j], 0.5f * sum1[j]);

    // ---- layer 3: per-wave partial over its own s2 slice (registers) ----
    float pw[4] = {0.f, 0.f, 0.f, 0.f};
    {
        const float* __restrict__ pb = &g_P[4400 + 8 * w];
#pragma unroll
        for (int k = 0; k < 8; ++k) {
            if (8 * w + k < 30) {      // wave-uniform guard (skips pads)
                const float ww = pb[k], ph = pb[32 + k], C = pb[64 + k];
                float x0 = sinp(fmaf(ww, tv[0], ph));
                float x1 = sinp(fmaf(ww, tv[1], ph));
                float x2 = fmaf(C, x1, -x0);
                float x3 = fmaf(C, x2, -x1);
                // out = sum (0.5*sin + 0.5) * s2
                pw[0] = fmaf(fmaf(0.5f, x0, 0.5f), s2r[k][0], pw[0]);
                pw[1] = fmaf(fmaf(0.5f, x1, 0.5f), s2r[k][1], pw[1]);
                pw[2] = fmaf(fmaf(0.5f, x2, 0.5f), s2r[k][2], pw[2]);
                pw[3] = fmaf(fmaf(0.5f, x3, 0.5f), s2r[k][3], pw[3]);
            }
        }
    }
    *(v4f*)&shp[w][l][0] = (v4f){pw[0], pw[1], pw[2], pw[3]};
    __syncthreads();

    // cross-wave reduce: wave w handles j == w
    const float r = (shp[0][l][w] + shp[1][l][w]) + (shp[2][l][w] + shp[3][l][w]);
    const int tt = tb + l + 64 * w;
    if (tt < T_TOTAL) out[tt] = r;
}

extern "C" void kernel_launch(void* const* d_in, const int* in_sizes, int n_in,
                              void* d_out, int out_size, void* d_ws, size_t ws_size,
                              hipStream_t stream) {
    (void)in_sizes; (void)n_in; (void)d_ws; (void)ws_size; (void)out_size;
    const float* A0    = (const float*)d_in[1];
    const float* w0    = (const float*)d_in[2];
    const float* phi0  = (const float*)d_in[3];
    const float* wc0   = (const float*)d_in[4];
    const float* phic0 = (const float*)d_in[5];
    const float* w1    = (const float*)d_in[6];
    const float* phi1  = (const float*)d_in[7];
    const float* wc1   = (const float*)d_in[8];
    const float* phic1 = (const float*)d_in[9];
    const float* w2    = (const float*)d_in[10];
    const float* phi2  = (const float*)d_in[11];
    const float* wc2   = (const float*)d_in[12];
    const float* phic2 = (const float*)d_in[13];
    const float* w3    = (const float*)d_in[14];
    const float* phi3  = (const float*)d_in[15];
    const float* wc3   = (const float*)d_in[16];
    const float* phic3 = (const float*)d_in[17];

    float* out = (float*)d_out;

    hipLaunchKernelGGL(prep_kernel, dim3(6), dim3(256), 0, stream,
                       A0, w0, phi0, wc0, phic0,
                       w1, phi1, wc1, phic1,
                       w2, phi2, wc2, phic2,
                       w3, phi3, wc3, phic3);

    const int grid = (T_TOTAL + 255) / 256;   // 782 (tail block: j=0 only valid)
    hipLaunchKernelGGL(wave_main, dim3(grid), dim3(256), 0, stream, out);
}

// Round 7
// 52.120 us; speedup vs baseline: 1.3750x; 1.0494x over previous
//
#include <hip/hip_runtime.h>
#include <hip/hip_bf16.h>

#define T_TOTAL 200000

typedef float v4f __attribute__((ext_vector_type(4)));

// Parameter block layout (floats), phases in REVOLUTIONS, +0.25-shifted so
// sin(theta) = cos(2*pi*(fract(rev)-0.5)) (even poly, no sign fixup):
// [0..23]   ww0'   [24..47] ph0'+0.25   [48..71] C0=2cos(w*64d)  [72..95] A0
//           (24 n-slots, pads n>=20: ww=0 ph=0.25 C=2 A=0)
// [96..2015]   layer1: per n<20, 96-float block at 96+96n:
//              [+m]=ww1'  [+32+m]=ph1'+0.25  [+64+m]=C1, m<32 (pads m>=25)
// [2016..4415] layer2: per n<25, 96-float block at 2016+96n (pads m>=30)
// [4416..4511] layer3: [+k]=ww3' [+32+k]=ph3'+0.25 [+64+k]=C3, k<32 (pads>=30)
__device__ float g_P[4512];

// sin(2*pi*rev) via even poly: cos(2*pi*h), h = fract(rev)-0.5. |err| ~= 4e-5.
__device__ __forceinline__ float sinp(float rev) {
    float g = __builtin_amdgcn_fractf(rev);
    float h = g - 0.5f;
    float u = h * h;
    float p = fmaf(45.621248f, u, -82.391040f);
    p = fmaf(p, u, 64.671616f);
    p = fmaf(p, u, -19.730960f);
    p = fmaf(p, u, 0.9999618f);
    return p;
}

__global__ void prep_kernel(
    const float* __restrict__ A0,
    const float* __restrict__ w0, const float* __restrict__ phi0,
    const float* __restrict__ wc0, const float* __restrict__ phic0,
    const float* __restrict__ w1, const float* __restrict__ phi1,
    const float* __restrict__ wc1, const float* __restrict__ phic1,
    const float* __restrict__ w2, const float* __restrict__ phi2,
    const float* __restrict__ wc2, const float* __restrict__ phic2,
    const float* __restrict__ w3, const float* __restrict__ phi3,
    const float* __restrict__ wc3, const float* __restrict__ phic3)
{
    const int tid = blockIdx.x * blockDim.x + threadIdx.x;
    const int stride = blockDim.x * gridDim.x;

    const double I2PI = 0.15915494309189535;
    const double D64  = 64.0 * 999.0 / 199999.0;   // tv-step between j's

    const double ws0 = fmax((double)wc0[0], 0.0), ps0 = fmax((double)phic0[0], 0.0);
    const double ws1 = fmax((double)wc1[0], 0.0), ps1 = fmax((double)phic1[0], 0.0);
    const double ws2 = fmax((double)wc2[0], 0.0), ps2 = fmax((double)phic2[0], 0.0);
    const double ws3 = fmax((double)wc3[0], 0.0), ps3 = fmax((double)phic3[0], 0.0);

    for (int n = tid; n < 24; n += stride) {
        float wwf = 0.0f, phf = 0.25f, cf = 2.0f, af = 0.0f;
        if (n < 20) {
            double wr = fmax((double)w0[n], 0.0) + ws0;
            wwf = (float)(wr * I2PI);
            phf = (float)((fmax((double)phi0[n], 0.0) + ps0) * I2PI + 0.25);
            cf  = (float)(2.0 * cos(wr * D64));
            af  = A0[n];
        }
        g_P[n]      = wwf;
        g_P[24 + n] = phf;
        g_P[48 + n] = cf;
        g_P[72 + n] = af;
    }
    for (int k = tid; k < 20 * 32; k += stride) {
        const int n = k >> 5, m = k & 31;
        float wwf = 0.0f, phf = 0.25f, cf = 2.0f;
        if (m < 25) {
            const int s = m * 20 + n;
            double wr = fmax((double)w1[s], 0.0) + ws1;
            wwf = (float)(wr * I2PI);
            phf = (float)((fmax((double)phi1[s], 0.0) + ps1) * I2PI + 0.25);
            cf  = (float)(2.0 * cos(wr * D64));
        }
        g_P[96 + 96 * n + m]      = wwf;
        g_P[96 + 96 * n + 32 + m] = phf;
        g_P[96 + 96 * n + 64 + m] = cf;
    }
    for (int k = tid; k < 25 * 32; k += stride) {
        const int n = k >> 5, m = k & 31;
        float wwf = 0.0f, phf = 0.25f, cf = 2.0f;
        if (m < 30) {
            const int s = m * 25 + n;
            double wr = fmax((double)w2[s], 0.0) + ws2;
            wwf = (float)(wr * I2PI);
            phf = (float)((fmax((double)phi2[s], 0.0) + ps2) * I2PI + 0.25);
            cf  = (float)(2.0 * cos(wr * D64));
        }
        g_P[2016 + 96 * n + m]      = wwf;
        g_P[2016 + 96 * n + 32 + m] = phf;
        g_P[2016 + 96 * n + 64 + m] = cf;
    }
    for (int k = tid; k < 32; k += stride) {
        float wwf = 0.0f, phf = 0.25f, cf = 2.0f;
        if (k < 30) {
            double wr = fmax((double)w3[k], 0.0) + ws3;
            wwf = (float)(wr * I2PI);
            phf = (float)((fmax((double)phi3[k], 0.0) + ps3) * I2PI + 0.25);
            cf  = (float)(2.0 * cos(wr * D64));
        }
        g_P[4416 + k]      = wwf;
        g_P[4416 + 32 + k] = phf;
        g_P[4416 + 64 + k] = cf;
    }
}

// Block = 512 threads = 8 waves covering 256 t-values: t = tb + lane + 64*j,
// j=0..3 per thread. Per (m,n): j=0,1 direct poly, j=2,3 via 1-fma Chebyshev
// recurrence x_{j+1} = C*x_j - x_{j-1}. Wave w owns m = 4w..4w+3 in layers
// 1-3 (m padded to 32; pads evaluate to sin=0). shp aliases sh0 (dead after
// layer 1) so LDS stays 50176 B -> 3 blocks/CU x 8 waves = 24 waves/CU.
__launch_bounds__(512)
__global__ void wave_main(float* __restrict__ out)
{
    __shared__ float smem[12544];
    float* const sh0 = smem;          // [24][64][4] = 6144 floats
    float* const sh1 = smem + 6144;   // [25][64][4] = 6400 floats
    float* const shp = smem;          // [8][64][4]  = 2048 floats (alias sh0)

    const int l = threadIdx.x & 63;
    const int w = __builtin_amdgcn_readfirstlane(threadIdx.x >> 6);
    const int tb = blockIdx.x * 256;
    const float STEP = 999.0f / 199999.0f;

    float tv[4];
#pragma unroll
    for (int j = 0; j < 4; ++j)
        tv[j] = fmaf((float)(tb + l + 64 * j), STEP, 1.0f);

    // ---- layer 0: wave w computes n = 3w..3w+2 (24 padded slots) ----
#pragma unroll
    for (int i = 0; i < 3; ++i) {
        const int n = 3 * w + i;
        const float ww = g_P[n], ph = g_P[24 + n], C = g_P[48 + n], A = g_P[72 + n];
        float x0 = A * sinp(fmaf(ww, tv[0], ph));
        float x1 = A * sinp(fmaf(ww, tv[1], ph));
        float x2 = fmaf(C, x1, -x0);
        float x3 = fmaf(C, x2, -x1);
        *(v4f*)&sh0[n * 256 + l * 4] = (v4f){x0, x1, x2, x3};
    }
    __syncthreads();

    // ---- layer 1: wave w owns m = 4w+k, k<4 (pad 32) ----
    float acc1[4][4] = {};
    float sum0[4] = {0.f, 0.f, 0.f, 0.f};
#pragma clang loop unroll(disable)
    for (int n = 0; n < 20; ++n) {
        const v4f s0 = *(const v4f*)&sh0[n * 256 + l * 4];
#pragma unroll
        for (int j = 0; j < 4; ++j) sum0[j] += s0[j];
        const float* __restrict__ pb = &g_P[96 + 96 * n + 4 * w];
#pragma unroll
        for (int k = 0; k < 4; ++k) {
            const float ww = pb[k], ph = pb[32 + k], C = pb[64 + k];
            float x0 = sinp(fmaf(ww, tv[0], ph));
            float x1 = sinp(fmaf(ww, tv[1], ph));
            float x2 = fmaf(C, x1, -x0);
            float x3 = fmaf(C, x2, -x1);
            acc1[k][0] = fmaf(x0, s0[0], acc1[k][0]);
            acc1[k][1] = fmaf(x1, s0[1], acc1[k][1]);
            acc1[k][2] = fmaf(x2, s0[2], acc1[k][2]);
            acc1[k][3] = fmaf(x3, s0[3], acc1[k][3]);
        }
    }
#pragma unroll
    for (int k = 0; k < 4; ++k) {
        if (4 * w + k < 25) {          // wave-uniform guard
            v4f v;
#pragma unroll
            for (int j = 0; j < 4; ++j) v[j] = fmaf(0.5f, acc1[k][j], 0.5f * sum0[j]);
            *(v4f*)&sh1[(4 * w + k) * 256 + l * 4] = v;
        }
    }
    __syncthreads();

    // ---- layer 2: wave w owns m = 4w+k, k<4 (pad 32); s2 stays in regs ----
    float acc2[4][4] = {};
    float sum1[4] = {0.f, 0.f, 0.f, 0.f};
#pragma clang loop unroll(disable)
    for (int n = 0; n < 25; ++n) {
        const v4f s1 = *(const v4f*)&sh1[n * 256 + l * 4];
#pragma unroll
        for (int j = 0; j < 4; ++j) sum1[j] += s1[j];
        const float* __restrict__ pb = &g_P[2016 + 96 * n + 4 * w];
#pragma unroll
        for (int k = 0; k < 4; ++k) {
            const float ww = pb[k], ph = pb[32 + k], C = pb[64 + k];
            float x0 = sinp(fmaf(ww, tv[0], ph));
            float x1 = sinp(fmaf(ww, tv[1], ph));
            float x2 = fmaf(C, x1, -x0);
            float x3 = fmaf(C, x2, -x1);
            acc2[k][0] = fmaf(x0, s1[0], acc2[k][0]);
            acc2[k][1] = fmaf(x1, s1[1], acc2[k][1]);
            acc2[k][2] = fmaf(x2, s1[2], acc2[k][2]);
            acc2[k][3] = fmaf(x3, s1[3], acc2[k][3]);
        }
    }
    float s2r[4][4];
#pragma unroll
    for (int k = 0; k < 4; ++k)
#pragma unroll
        for (int j = 0; j < 4; ++j)
            s2r[k][j] = fmaf(0.5f, acc2[k][j], 0.5f * sum1[j]);

    // ---- layer 3: per-wave partial over its own m-slice (registers) ----
    float pw[4] = {0.f, 0.f, 0.f, 0.f};
    {
        const float* __restrict__ pb = &g_P[4416 + 4 * w];
#pragma unroll
        for (int k = 0; k < 4; ++k) {
            if (4 * w + k < 30) {      // wave-uniform guard (skips pads)
                const float ww = pb[k], ph = pb[32 + k], C = pb[64 + k];
                float x0 = sinp(fmaf(ww, tv[0], ph));
                float x1 = sinp(fmaf(ww, tv[1], ph));
                float x2 = fmaf(C, x1, -x0);
                float x3 = fmaf(C, x2, -x1);
                pw[0] = fmaf(fmaf(0.5f, x0, 0.5f), s2r[k][0], pw[0]);
                pw[1] = fmaf(fmaf(0.5f, x1, 0.5f), s2r[k][1], pw[1]);
                pw[2] = fmaf(fmaf(0.5f, x2, 0.5f), s2r[k][2], pw[2]);
                pw[3] = fmaf(fmaf(0.5f, x3, 0.5f), s2r[k][3], pw[3]);
            }
        }
    }
    __syncthreads();                   // sh0 reads done long ago; safe to alias
    *(v4f*)&shp[w * 256 + l * 4] = (v4f){pw[0], pw[1], pw[2], pw[3]};
    __syncthreads();

    // cross-wave reduce: wave w (w<4) handles j == w
    if (w < 4) {
        float r = 0.0f;
#pragma unroll
        for (int w2 = 0; w2 < 8; ++w2)
            r += shp[w2 * 256 + l * 4 + w];
        const int tt = tb + l + 64 * w;
        if (tt < T_TOTAL) out[tt] = r;
    }
}

extern "C" void kernel_launch(void* const* d_in, const int* in_sizes, int n_in,
                              void* d_out, int out_size, void* d_ws, size_t ws_size,
                              hipStream_t stream) {
    (void)in_sizes; (void)n_in; (void)d_ws; (void)ws_size; (void)out_size;
    const float* A0    = (const float*)d_in[1];
    const float* w0    = (const float*)d_in[2];
    const float* phi0  = (const float*)d_in[3];
    const float* wc0   = (const float*)d_in[4];
    const float* phic0 = (const float*)d_in[5];
    const float* w1    = (const float*)d_in[6];
    const float* phi1  = (const float*)d_in[7];
    const float* wc1   = (const float*)d_in[8];
    const float* phic1 = (const float*)d_in[9];
    const float* w2    = (const float*)d_in[10];
    const float* phi2  = (const float*)d_in[11];
    const float* wc2   = (const float*)d_in[12];
    const float* phic2 = (const float*)d_in[13];
    const float* w3    = (const float*)d_in[14];
    const float* phi3  = (const float*)d_in[15];
    const float* wc3   = (const float*)d_in[16];
    const float* phic3 = (const float*)d_in[17];

    float* out = (float*)d_out;

    hipLaunchKernelGGL(prep_kernel, dim3(6), dim3(256), 0, stream,
                       A0, w0, phi0, wc0, phic0,
                       w1, phi1, wc1, phic1,
                       w2, phi2, wc2, phic2,
                       w3, phi3, wc3, phic3);

    const int grid = (T_TOTAL + 255) / 256;   // 782
    hipLaunchKernelGGL(wave_main, dim3(grid), dim3(512), 0, stream, out);
}